// Round 1
// baseline (1065.820 us; speedup 1.0000x reference)
//
#include <hip/hip_runtime.h>
#include <math.h>

constexpr int B = 16, T = 2048, C = 256;
constexpr float TH = 1.0f;

// ---------------------------------------------------------------------------
// Kernel 1: fuse conv_w [C_out, C_in, 3] with lin_w [C_out] -> w2f[3*C] and
// bias2 = lin_w . conv_b + lin_b.
// w2f layout: [k][i] so that alpha pre-activation is a dot of 768 contiguous
// h elements (rows t-1, t, t+1 of the [T, C] input).
// ---------------------------------------------------------------------------
__global__ void w2_kernel(const float* __restrict__ conv_w,
                          const float* __restrict__ conv_b,
                          const float* __restrict__ lin_w,
                          const float* __restrict__ lin_b,
                          float* __restrict__ w2f,
                          float* __restrict__ bias2) {
    int i = threadIdx.x;
    if (i >= C) return;
    float s0 = 0.f, s1 = 0.f, s2 = 0.f;
    for (int o = 0; o < C; ++o) {
        float lw = lin_w[o];
        const float* cw = conv_w + ((size_t)o * C + i) * 3;
        s0 = fmaf(lw, cw[0], s0);
        s1 = fmaf(lw, cw[1], s1);
        s2 = fmaf(lw, cw[2], s2);
    }
    w2f[0 * C + i] = s0;
    w2f[1 * C + i] = s1;
    w2f[2 * C + i] = s2;
    if (i == 0) {
        float s = lin_b[0];
        for (int o = 0; o < C; ++o) s = fmaf(lin_w[o], conv_b[o], s);
        *bias2 = s;
    }
}

// ---------------------------------------------------------------------------
// Kernel 2: alpha[b,t] = sigmoid( dot(w2f, h[b, t-1 : t+2, :]) + bias2 )
// One wave (64 lanes) per (b,t); 12 elements per lane covers 768.
// Also accumulates loss_pen = sum(alpha) via one atomic per wave.
// ---------------------------------------------------------------------------
__global__ void alpha_kernel(const float* __restrict__ h,
                             const float* __restrict__ w2f,
                             const float* __restrict__ bias2,
                             float* __restrict__ alpha,
                             float* __restrict__ loss) {
    int gid  = blockIdx.x * blockDim.x + threadIdx.x;
    int wave = gid >> 6;
    int lane = gid & 63;
    if (wave >= B * T) return;
    int b = wave >> 11;       // wave / T   (T = 2048)
    int t = wave & (T - 1);   // wave % T
    const float* hb = h + (size_t)b * T * C;
    long base = ((long)t - 1) * C;
    float s = 0.f;
#pragma unroll
    for (int j = 0; j < 12; ++j) {
        int e = lane + 64 * j;
        // zero-pad at t==0 (skip first C elems) and t==T-1 (skip last C elems)
        bool ok = (t > 0 || e >= C) && (t < T - 1 || e < 2 * C);
        if (ok) s = fmaf(hb[base + e], w2f[e], s);
    }
#pragma unroll
    for (int off = 32; off > 0; off >>= 1) s += __shfl_down(s, off);
    if (lane == 0) {
        float a = 1.f / (1.f + expf(-(s + *bias2)));
        alpha[wave] = a;
        atomicAdd(loss, a);
    }
}

// ---------------------------------------------------------------------------
// Kernel 3: the CIF scan. One block per batch row, one thread per channel.
// Replicates the reference recurrence EXACTLY (same float op order) so fire
// decisions match. Each output row is written at most once -> plain stores.
// ---------------------------------------------------------------------------
__global__ void cif_scan(const float* __restrict__ h,
                         const float* __restrict__ alpha,
                         float* __restrict__ out) {
    int b = blockIdx.x;
    int c = threadIdx.x;
    const float* hb = h + (size_t)b * T * C;
    const float* ab = alpha + (size_t)b * T;
    float* ob = out + (size_t)b * T * C;

    float aa   = ab[0];
    float hacc = aa * hb[c];
    int   idx  = 0;
    for (int t = 1; t < T; ++t) {
        float at = ab[t];
        float ht = hb[(size_t)t * C + c];
        float aa_new = aa + at;
        float a1 = TH - aa;
        if (aa_new >= TH) {
            ob[(size_t)idx * C + c] = hacc + a1 * ht;
            ++idx;
            float rem = at - a1;   // == au - a1, matches reference
            aa   = rem;
            hacc = rem * ht;
        } else {
            aa   = aa_new;
            hacc = fmaf(at, ht, hacc);
        }
    }
    if (aa >= 0.5f * TH) ob[(size_t)idx * C + c] = hacc;
}

// ---------------------------------------------------------------------------
extern "C" void kernel_launch(void* const* d_in, const int* in_sizes, int n_in,
                              void* d_out, int out_size, void* d_ws, size_t ws_size,
                              hipStream_t stream) {
    const float* h      = (const float*)d_in[0];
    // d_in[1] = hs_mask (unused by the math)
    const float* conv_w = (const float*)d_in[2];
    const float* conv_b = (const float*)d_in[3];
    const float* lin_w  = (const float*)d_in[4];
    const float* lin_b  = (const float*)d_in[5];

    float* out  = (float*)d_out;
    float* loss = out + (size_t)B * T * C;   // last element of d_out
    (void)loss;

    // workspace layout: w2f[768] | bias2[1] (pad to 1024) | alpha[B*T]
    float* w2f   = (float*)d_ws;
    float* bias2 = w2f + 768;
    float* alpha = w2f + 1024;

    // zero cs output + loss slot (rows >= length must be zero)
    hipMemsetAsync(d_out, 0, (size_t)out_size * sizeof(float), stream);

    hipLaunchKernelGGL(w2_kernel, dim3(1), dim3(256), 0, stream,
                       conv_w, conv_b, lin_w, lin_b, w2f, bias2);

    int nwaves = B * T;                       // one wave per (b,t)
    int blocks = (nwaves * 64) / 256;         // 4 waves per block
    hipLaunchKernelGGL(alpha_kernel, dim3(blocks), dim3(256), 0, stream,
                       h, w2f, bias2, alpha, out + (size_t)B * T * C);

    hipLaunchKernelGGL(cif_scan, dim3(B), dim3(C), 0, stream,
                       h, alpha, out);
}

// Round 2
// 1063.732 us; speedup vs baseline: 1.0020x; 1.0020x over previous
//
#include <hip/hip_runtime.h>
#include <math.h>

constexpr int B = 16, T = 2048, C = 256;
constexpr float TH = 1.0f;

// ---------------------------------------------------------------------------
// Kernel 1: fuse conv_w [C_out, C_in, 3] with lin_w [C_out] -> w2f[3*C] and
// bias2 = lin_w . conv_b + lin_b.
// w2f layout: [k][i] so that alpha pre-activation is a dot of 768 contiguous
// h elements (rows t-1, t, t+1 of the [T, C] input).
// ---------------------------------------------------------------------------
__global__ void w2_kernel(const float* __restrict__ conv_w,
                          const float* __restrict__ conv_b,
                          const float* __restrict__ lin_w,
                          const float* __restrict__ lin_b,
                          float* __restrict__ w2f,
                          float* __restrict__ bias2) {
    int i = threadIdx.x;
    if (i >= C) return;
    float s0 = 0.f, s1 = 0.f, s2 = 0.f;
    for (int o = 0; o < C; ++o) {
        float lw = lin_w[o];
        const float* cw = conv_w + ((size_t)o * C + i) * 3;
        s0 = fmaf(lw, cw[0], s0);
        s1 = fmaf(lw, cw[1], s1);
        s2 = fmaf(lw, cw[2], s2);
    }
    w2f[0 * C + i] = s0;
    w2f[1 * C + i] = s1;
    w2f[2 * C + i] = s2;
    if (i == 0) {
        float s = lin_b[0];
        for (int o = 0; o < C; ++o) s = fmaf(lin_w[o], conv_b[o], s);
        *bias2 = s;
    }
}

// ---------------------------------------------------------------------------
// Kernel 2: alpha[b,t] = sigmoid( dot(w2f, h[b, t-1 : t+2, :]) + bias2 )
// One wave (64 lanes) per (b,t); 12 elements per lane covers 768.
// Also accumulates loss_pen = sum(alpha) via one atomic per wave.
// ---------------------------------------------------------------------------
__global__ void alpha_kernel(const float* __restrict__ h,
                             const float* __restrict__ w2f,
                             const float* __restrict__ bias2,
                             float* __restrict__ alpha,
                             float* __restrict__ loss) {
    int gid  = blockIdx.x * blockDim.x + threadIdx.x;
    int wave = gid >> 6;
    int lane = gid & 63;
    if (wave >= B * T) return;
    int b = wave >> 11;       // wave / T   (T = 2048)
    int t = wave & (T - 1);   // wave % T
    const float* hb = h + (size_t)b * T * C;
    long base = ((long)t - 1) * C;
    float s = 0.f;
#pragma unroll
    for (int j = 0; j < 12; ++j) {
        int e = lane + 64 * j;
        // zero-pad at t==0 (skip first C elems) and t==T-1 (skip last C elems)
        bool ok = (t > 0 || e >= C) && (t < T - 1 || e < 2 * C);
        if (ok) s = fmaf(hb[base + e], w2f[e], s);
    }
#pragma unroll
    for (int off = 32; off > 0; off >>= 1) s += __shfl_down(s, off);
    if (lane == 0) {
        float a = 1.f / (1.f + expf(-(s + *bias2)));
        alpha[wave] = a;
        atomicAdd(loss, a);
    }
}

// ---------------------------------------------------------------------------
// Kernel 3: the CIF scan. One block per batch row, one thread per channel.
// Replicates the reference recurrence EXACTLY (same float op order) so fire
// decisions match. Each output row is written at most once -> plain stores.
// ---------------------------------------------------------------------------
__global__ void cif_scan(const float* __restrict__ h,
                         const float* __restrict__ alpha,
                         float* __restrict__ out) {
    int b = blockIdx.x;
    int c = threadIdx.x;
    const float* hb = h + (size_t)b * T * C;
    const float* ab = alpha + (size_t)b * T;
    float* ob = out + (size_t)b * T * C;

    float aa   = ab[0];
    float hacc = aa * hb[c];
    int   idx  = 0;
    for (int t = 1; t < T; ++t) {
        float at = ab[t];
        float ht = hb[(size_t)t * C + c];
        float aa_new = aa + at;
        float a1 = TH - aa;
        if (aa_new >= TH) {
            ob[(size_t)idx * C + c] = hacc + a1 * ht;
            ++idx;
            float rem = at - a1;   // == au - a1, matches reference
            aa   = rem;
            hacc = rem * ht;
        } else {
            aa   = aa_new;
            hacc = fmaf(at, ht, hacc);
        }
    }
    if (aa >= 0.5f * TH) ob[(size_t)idx * C + c] = hacc;
}

// ---------------------------------------------------------------------------
extern "C" void kernel_launch(void* const* d_in, const int* in_sizes, int n_in,
                              void* d_out, int out_size, void* d_ws, size_t ws_size,
                              hipStream_t stream) {
    const float* h      = (const float*)d_in[0];
    // d_in[1] = hs_mask (unused by the math)
    const float* conv_w = (const float*)d_in[2];
    const float* conv_b = (const float*)d_in[3];
    const float* lin_w  = (const float*)d_in[4];
    const float* lin_b  = (const float*)d_in[5];

    float* out  = (float*)d_out;
    float* loss = out + (size_t)B * T * C;   // last element of d_out
    (void)loss;

    // workspace layout: w2f[768] | bias2[1] (pad to 1024) | alpha[B*T]
    float* w2f   = (float*)d_ws;
    float* bias2 = w2f + 768;
    float* alpha = w2f + 1024;

    // zero cs output + loss slot (rows >= length must be zero)
    hipMemsetAsync(d_out, 0, (size_t)out_size * sizeof(float), stream);

    hipLaunchKernelGGL(w2_kernel, dim3(1), dim3(256), 0, stream,
                       conv_w, conv_b, lin_w, lin_b, w2f, bias2);

    int nwaves = B * T;                       // one wave per (b,t)
    int blocks = (nwaves * 64) / 256;         // 4 waves per block
    hipLaunchKernelGGL(alpha_kernel, dim3(blocks), dim3(256), 0, stream,
                       h, w2f, bias2, alpha, out + (size_t)B * T * C);

    hipLaunchKernelGGL(cif_scan, dim3(B), dim3(C), 0, stream,
                       h, alpha, out);
}

// Round 3
// 197.215 us; speedup vs baseline: 5.4044x; 5.3938x over previous
//
#include <hip/hip_runtime.h>
#include <math.h>

constexpr int B = 16, T = 2048, C = 256;

// ---------------------------------------------------------------------------
// Kernel 1: fuse conv_w [C_out, C_in, 3] with lin_w [C_out] -> w2f[3*C], and
// bias2 = lin_w . conv_b + lin_b. One wave per output element (769 waves).
// w2f layout [k][i] so alpha pre-activation is a dot of 768 contiguous floats.
// ---------------------------------------------------------------------------
__global__ void w2_kernel(const float* __restrict__ conv_w,
                          const float* __restrict__ conv_b,
                          const float* __restrict__ lin_w,
                          const float* __restrict__ lin_b,
                          float* __restrict__ w2f,
                          float* __restrict__ bias2) {
    int gid  = blockIdx.x * blockDim.x + threadIdx.x;
    int wv   = gid >> 6;
    int lane = gid & 63;
    if (wv > 768) return;
    float s = 0.f;
    if (wv < 768) {
        int i = wv & 255, k = wv >> 8;   // wv = k*256 + i
#pragma unroll
        for (int m = 0; m < 4; ++m) {
            int o = lane + 64 * m;
            s = fmaf(lin_w[o], conv_w[((size_t)o * C + i) * 3 + k], s);
        }
    } else {
#pragma unroll
        for (int m = 0; m < 4; ++m) {
            int o = lane + 64 * m;
            s = fmaf(lin_w[o], conv_b[o], s);
        }
    }
#pragma unroll
    for (int off = 32; off; off >>= 1) s += __shfl_down(s, off);
    if (lane == 0) {
        if (wv < 768) w2f[wv] = s;
        else          *bias2 = s + lin_b[0];
    }
}

// ---------------------------------------------------------------------------
// Kernel 2: alpha[b,t] = sigmoid( dot(w2f, h[b, t-1 : t+2, :]) + bias2 )
// One wave per (b,t); 12 elements per lane covers the 768-long dot.
// ---------------------------------------------------------------------------
__global__ void alpha_kernel(const float* __restrict__ h,
                             const float* __restrict__ w2f,
                             const float* __restrict__ bias2,
                             float* __restrict__ alpha) {
    int gid  = blockIdx.x * blockDim.x + threadIdx.x;
    int wave = gid >> 6;
    int lane = gid & 63;
    if (wave >= B * T) return;
    int b = wave >> 11;       // / T
    int t = wave & (T - 1);   // % T
    const float* hb = h + (size_t)b * T * C;
    long base = ((long)t - 1) * C;
    float s = 0.f;
#pragma unroll
    for (int j = 0; j < 12; ++j) {
        int e = lane + 64 * j;
        bool ok = (t > 0 || e >= C) && (t < T - 1 || e < 2 * C);
        if (ok) s = fmaf(hb[base + e], w2f[e], s);
    }
#pragma unroll
    for (int off = 32; off; off >>= 1) s += __shfl_down(s, off);
    if (lane == 0)
        alpha[wave] = 1.f / (1.f + expf(-(s + *bias2)));
}

// ---------------------------------------------------------------------------
// Kernel 3: exact reference scalar recurrence, one wave per batch row.
// Lanes cooperatively load 64 alphas, then all lanes redundantly walk the
// recurrence via __shfl broadcast (uniform branches, ~12 cyc/frame).
// Emits per-fire: frame F[j], boundary weights A1[j], REM[j]; per-batch K &
// tail flag; and loss_pen (sum of alpha) via one atomic per batch.
// ---------------------------------------------------------------------------
__global__ void fire_scan(const float* __restrict__ alpha,
                          int*   __restrict__ F,
                          float* __restrict__ A1,
                          float* __restrict__ REM,
                          int*   __restrict__ Kaux,
                          float* __restrict__ loss) {
    int b    = blockIdx.x;
    int lane = threadIdx.x;  // 0..63
    const float* ab = alpha + (size_t)b * T;
    int*   Fb = F   + (size_t)b * T;
    float* Ab = A1  + (size_t)b * T;
    float* Rb = REM + (size_t)b * T;

    float aa = 0.f;
    int   idx = 0;
    float lsum = 0.f;
    for (int t0 = 0; t0 < T; t0 += 64) {
        float aval = ab[t0 + lane];
        lsum += aval;
        for (int i = 0; i < 64; ++i) {
            float au = __shfl(aval, i);
            int t = t0 + i;
            if (t == 0) { aa = au; continue; }
            float aa_new = aa + au;
            float a1 = 1.0f - aa;
            if (aa_new >= 1.0f) {           // uniform branch across lanes
                // all lanes store identical values to identical addresses
                Fb[idx] = t;
                Ab[idx] = a1;
                Rb[idx] = au - a1;
                aa = au - a1;
                ++idx;
            } else {
                aa = aa_new;
            }
        }
    }
    if (lane == 0) {
        Kaux[2 * b]     = idx;
        Kaux[2 * b + 1] = (aa >= 0.5f) ? 1 : 0;
    }
#pragma unroll
    for (int off = 32; off; off >>= 1) lsum += __shfl_down(lsum, off);
    if (lane == 0) atomicAdd(loss, lsum);
}

// ---------------------------------------------------------------------------
// Kernel 4: gather. One wave per output row (b, j). Each lane owns 4 channels
// (float4). Accumulates in ascending-t order (matches reference hacc order):
//   out[j] = REM[j-1]*h[s]  +  sum_{s<t<e} alpha[t]*h[t]  +  A1[j]*h[e]
// Rows past the fire count are written as zeros (replaces the memset).
// ---------------------------------------------------------------------------
__global__ void gather_kernel(const float* __restrict__ h,
                              const float* __restrict__ alpha,
                              const int*   __restrict__ F,
                              const float* __restrict__ A1,
                              const float* __restrict__ REM,
                              const int*   __restrict__ Kaux,
                              float* __restrict__ out) {
    int gid  = blockIdx.x * blockDim.x + threadIdx.x;
    int wv   = gid >> 6;
    int lane = gid & 63;
    if (wv >= B * T) return;
    int b = wv >> 11;
    int j = wv & (T - 1);
    int K    = Kaux[2 * b];
    int tail = Kaux[2 * b + 1];
    float4* orow = (float4*)(out + ((size_t)b * T + j) * C) + lane;
    if (j > K || (j == K && !tail)) {
        *orow = make_float4(0.f, 0.f, 0.f, 0.f);
        return;
    }
    const float*  ab = alpha + (size_t)b * T;
    const float4* hb = (const float4*)(h + (size_t)b * T * C);
    const int*    Fb = F + (size_t)b * T;

    float4 acc;
    int t;
    if (j > 0) {
        int s = Fb[j - 1];
        float r = REM[(size_t)b * T + j - 1];
        float4 hv = hb[(size_t)s * 64 + lane];
        acc = make_float4(r * hv.x, r * hv.y, r * hv.z, r * hv.w);
        t = s + 1;
    } else {
        acc = make_float4(0.f, 0.f, 0.f, 0.f);
        t = 0;
    }
    int mid_end = (j == K) ? T : Fb[j];
    for (; t < mid_end; ++t) {
        float a = ab[t];
        float4 hv = hb[(size_t)t * 64 + lane];
        acc.x = fmaf(a, hv.x, acc.x);
        acc.y = fmaf(a, hv.y, acc.y);
        acc.z = fmaf(a, hv.z, acc.z);
        acc.w = fmaf(a, hv.w, acc.w);
    }
    if (j < K) {
        float a1 = A1[(size_t)b * T + j];
        float4 hv = hb[(size_t)mid_end * 64 + lane];
        acc.x = fmaf(a1, hv.x, acc.x);
        acc.y = fmaf(a1, hv.y, acc.y);
        acc.z = fmaf(a1, hv.z, acc.z);
        acc.w = fmaf(a1, hv.w, acc.w);
    }
    *orow = acc;
}

// ---------------------------------------------------------------------------
extern "C" void kernel_launch(void* const* d_in, const int* in_sizes, int n_in,
                              void* d_out, int out_size, void* d_ws, size_t ws_size,
                              hipStream_t stream) {
    const float* h      = (const float*)d_in[0];
    // d_in[1] = hs_mask (unused by the math)
    const float* conv_w = (const float*)d_in[2];
    const float* conv_b = (const float*)d_in[3];
    const float* lin_w  = (const float*)d_in[4];
    const float* lin_b  = (const float*)d_in[5];

    float* out  = (float*)d_out;
    float* loss = out + (size_t)B * T * C;   // last element of d_out

    // workspace layout (floats)
    float* w2f   = (float*)d_ws;              // [0, 768)
    float* bias2 = w2f + 768;                 // [768]
    float* alpha = w2f + 1024;                // [1024, 1024+B*T)
    float* A1    = alpha + B * T;             // B*T
    float* REM   = A1 + B * T;                // B*T
    int*   F     = (int*)(REM + B * T);       // B*T ints
    int*   Kaux  = F + B * T;                 // 2*B ints

    // zero only the loss slot; gather writes every cs row (zeros included)
    hipMemsetAsync(loss, 0, sizeof(float), stream);

    hipLaunchKernelGGL(w2_kernel, dim3(193), dim3(256), 0, stream,
                       conv_w, conv_b, lin_w, lin_b, w2f, bias2);

    hipLaunchKernelGGL(alpha_kernel, dim3(B * T / 4), dim3(256), 0, stream,
                       h, w2f, bias2, alpha);

    hipLaunchKernelGGL(fire_scan, dim3(B), dim3(64), 0, stream,
                       alpha, F, A1, REM, Kaux, loss);

    hipLaunchKernelGGL(gather_kernel, dim3(B * T / 4), dim3(256), 0, stream,
                       h, alpha, F, A1, REM, Kaux, out);
}

// Round 4
// 173.859 us; speedup vs baseline: 6.1304x; 1.1343x over previous
//
#include <hip/hip_runtime.h>
#include <math.h>

constexpr int B = 16, T = 2048, C = 256;

// ---------------------------------------------------------------------------
// Kernel 1: fuse conv_w [C_out, C_in, 3] with lin_w [C_out] -> w2f[3*C], and
// bias2 = lin_w . conv_b + lin_b. One wave per output element (769 waves).
// w2f layout [k][i]: preact(t) = sum_i w2f[0][i]*h[t-1,i] + w2f[1][i]*h[t,i]
//                              + w2f[2][i]*h[t+1,i] + bias2
// ---------------------------------------------------------------------------
__global__ void w2_kernel(const float* __restrict__ conv_w,
                          const float* __restrict__ conv_b,
                          const float* __restrict__ lin_w,
                          const float* __restrict__ lin_b,
                          float* __restrict__ w2f,
                          float* __restrict__ bias2) {
    int gid  = blockIdx.x * blockDim.x + threadIdx.x;
    int wv   = gid >> 6;
    int lane = gid & 63;
    if (wv > 768) return;
    float s = 0.f;
    if (wv < 768) {
        int i = wv & 255, k = wv >> 8;   // wv = k*256 + i
#pragma unroll
        for (int m = 0; m < 4; ++m) {
            int o = lane + 64 * m;
            s = fmaf(lin_w[o], conv_w[((size_t)o * C + i) * 3 + k], s);
        }
    } else {
#pragma unroll
        for (int m = 0; m < 4; ++m) {
            int o = lane + 64 * m;
            s = fmaf(lin_w[o], conv_b[o], s);
        }
    }
#pragma unroll
    for (int off = 32; off; off >>= 1) s += __shfl_down(s, off);
    if (lane == 0) {
        if (wv < 768) w2f[wv] = s;
        else          *bias2 = s + lin_b[0];
    }
}

// ---------------------------------------------------------------------------
// Kernel 2: per-frame partial dots. One wave per (b,t); lane owns 4 channels.
// P_k[bt] = dot(w2f[k], h[b,t,:]).  h is read exactly once (32 MB).
// ---------------------------------------------------------------------------
__global__ void pdot_kernel(const float* __restrict__ h,
                            const float* __restrict__ w2f,
                            float* __restrict__ P0,
                            float* __restrict__ P1,
                            float* __restrict__ P2) {
    int gid  = blockIdx.x * blockDim.x + threadIdx.x;
    int wv   = gid >> 6;
    int lane = gid & 63;
    if (wv >= B * T) return;
    const float4* w4 = (const float4*)w2f;
    float4 w0 = w4[lane], w1 = w4[64 + lane], w2 = w4[128 + lane];
    float4 hv = ((const float4*)h)[(size_t)wv * 64 + lane];
    float s0 = hv.x * w0.x + hv.y * w0.y + hv.z * w0.z + hv.w * w0.w;
    float s1 = hv.x * w1.x + hv.y * w1.y + hv.z * w1.z + hv.w * w1.w;
    float s2 = hv.x * w2.x + hv.y * w2.y + hv.z * w2.z + hv.w * w2.w;
#pragma unroll
    for (int off = 32; off; off >>= 1) {
        s0 += __shfl_down(s0, off);
        s1 += __shfl_down(s1, off);
        s2 += __shfl_down(s2, off);
    }
    if (lane == 0) { P0[wv] = s0; P1[wv] = s1; P2[wv] = s2; }
}

// ---------------------------------------------------------------------------
// Kernel 3: alpha[bt] = sigmoid(P0[bt-1] + P1[bt] + P2[bt+1] + bias2),
// edges dropped. Also accumulates loss_pen = sum(alpha).
// ---------------------------------------------------------------------------
__global__ void combine_kernel(const float* __restrict__ P0,
                               const float* __restrict__ P1,
                               const float* __restrict__ P2,
                               const float* __restrict__ bias2,
                               float* __restrict__ alpha,
                               float* __restrict__ loss) {
    int tid = blockIdx.x * blockDim.x + threadIdx.x;
    if (tid >= B * T) return;
    int t = tid & (T - 1);
    float pre = P1[tid] + *bias2;
    if (t > 0)     pre += P0[tid - 1];
    if (t < T - 1) pre += P2[tid + 1];
    float a = 1.f / (1.f + expf(-pre));
    alpha[tid] = a;
    float s = a;
#pragma unroll
    for (int off = 32; off; off >>= 1) s += __shfl_down(s, off);
    if ((threadIdx.x & 63) == 0) atomicAdd(loss, s);
}

// ---------------------------------------------------------------------------
// Kernel 4: exact reference scalar recurrence. ONE LANE PER BATCH (16 lanes,
// single wave). 8-deep float4 register pipeline hides the alpha-load latency;
// the dependent chain is ~10 cyc/frame. Fire decisions bit-match the
// reference op order: a1 = 1-aa; rem = au-a1; aa' = fired ? rem : aa+au.
// ---------------------------------------------------------------------------
__global__ void fire_scan(const float* __restrict__ alpha,
                          int*   __restrict__ F,
                          float* __restrict__ A1,
                          float* __restrict__ REM,
                          int*   __restrict__ Kaux) {
    int b = threadIdx.x;
    if (b >= B) return;
    const float4* ab4 = (const float4*)(alpha + (size_t)b * T);
    int*   Fb = F   + (size_t)b * T;
    float* Ab = A1  + (size_t)b * T;
    float* Rb = REM + (size_t)b * T;

    float aa = 0.f;
    int   idx = 0;

    float4 pf[8];
#pragma unroll
    for (int u = 0; u < 8; ++u) pf[u] = ab4[u];

    constexpr int NG = T / 4;  // 512 groups of 4 frames
    for (int gg = 0; gg < NG; gg += 8) {
#pragma unroll
        for (int u = 0; u < 8; ++u) {
            int g = gg + u;
            float4 cur = pf[u];
            int pre = g + 8 < NG ? g + 8 : NG - 1;
            pf[u] = ab4[pre];   // refill (static reg index, clamped addr)

#pragma unroll
            for (int j = 0; j < 4; ++j) {
                float au = (j == 0) ? cur.x : (j == 1) ? cur.y
                                            : (j == 2) ? cur.z : cur.w;
                int t = 4 * g + j;
                if (t == 0) { aa = au; continue; }   // init, never fires
                float aa_new = aa + au;
                float a1  = 1.0f - aa;
                float rem = au - a1;
                if (aa_new >= 1.0f) {
                    Fb[idx] = t;
                    Ab[idx] = a1;
                    Rb[idx] = rem;
                    ++idx;
                    aa = rem;
                } else {
                    aa = aa_new;
                }
            }
        }
    }
    Kaux[2 * b]     = idx;
    Kaux[2 * b + 1] = (aa >= 0.5f) ? 1 : 0;
}

// ---------------------------------------------------------------------------
// Kernel 5: gather. One wave per output row (b, j); lane owns 4 channels.
// out[j] = REM[j-1]*h[s] + sum_{s<t<e} alpha[t]*h[t] + A1[j]*h[e],
// accumulated in ascending-t order (matches reference hacc order).
// Rows past the fire count are written as zeros (no memset needed).
// ---------------------------------------------------------------------------
__global__ void gather_kernel(const float* __restrict__ h,
                              const float* __restrict__ alpha,
                              const int*   __restrict__ F,
                              const float* __restrict__ A1,
                              const float* __restrict__ REM,
                              const int*   __restrict__ Kaux,
                              float* __restrict__ out) {
    int gid  = blockIdx.x * blockDim.x + threadIdx.x;
    int wv   = gid >> 6;
    int lane = gid & 63;
    if (wv >= B * T) return;
    int b = wv >> 11;
    int j = wv & (T - 1);
    int K    = Kaux[2 * b];
    int tail = Kaux[2 * b + 1];
    float4* orow = (float4*)(out + ((size_t)b * T + j) * C) + lane;
    if (j > K || (j == K && !tail)) {
        *orow = make_float4(0.f, 0.f, 0.f, 0.f);
        return;
    }
    const float*  ab = alpha + (size_t)b * T;
    const float4* hb = (const float4*)(h + (size_t)b * T * C);
    const int*    Fb = F + (size_t)b * T;

    float4 acc;
    int t;
    if (j > 0) {
        int s = Fb[j - 1];
        float r = REM[(size_t)b * T + j - 1];
        float4 hv = hb[(size_t)s * 64 + lane];
        acc = make_float4(r * hv.x, r * hv.y, r * hv.z, r * hv.w);
        t = s + 1;
    } else {
        acc = make_float4(0.f, 0.f, 0.f, 0.f);
        t = 0;
    }
    int mid_end = (j == K) ? T : Fb[j];
    for (; t < mid_end; ++t) {
        float a = ab[t];
        float4 hv = hb[(size_t)t * 64 + lane];
        acc.x = fmaf(a, hv.x, acc.x);
        acc.y = fmaf(a, hv.y, acc.y);
        acc.z = fmaf(a, hv.z, acc.z);
        acc.w = fmaf(a, hv.w, acc.w);
    }
    if (j < K) {
        float a1 = A1[(size_t)b * T + j];
        float4 hv = hb[(size_t)mid_end * 64 + lane];
        acc.x = fmaf(a1, hv.x, acc.x);
        acc.y = fmaf(a1, hv.y, acc.y);
        acc.z = fmaf(a1, hv.z, acc.z);
        acc.w = fmaf(a1, hv.w, acc.w);
    }
    *orow = acc;
}

// ---------------------------------------------------------------------------
extern "C" void kernel_launch(void* const* d_in, const int* in_sizes, int n_in,
                              void* d_out, int out_size, void* d_ws, size_t ws_size,
                              hipStream_t stream) {
    const float* h      = (const float*)d_in[0];
    // d_in[1] = hs_mask (unused by the math)
    const float* conv_w = (const float*)d_in[2];
    const float* conv_b = (const float*)d_in[3];
    const float* lin_w  = (const float*)d_in[4];
    const float* lin_b  = (const float*)d_in[5];

    float* out  = (float*)d_out;
    float* loss = out + (size_t)B * T * C;   // last element of d_out

    // workspace layout (floats):
    //   w2f[768] | bias2 (pad to 1024) | alpha[B*T] | P0[B*T] | P1[B*T] | P2[B*T]
    // P0/P1/P2 are consumed by combine_kernel BEFORE fire_scan writes
    // F/A1/REM, so those alias the P buffers.
    float* w2f   = (float*)d_ws;
    float* bias2 = w2f + 768;
    float* alpha = w2f + 1024;
    float* P0    = alpha + B * T;
    float* P1    = P0 + B * T;
    float* P2    = P1 + B * T;
    int*   F     = (int*)P0;                  // alias (fire_scan phase)
    float* A1    = P1;                        // alias
    float* REM   = P2;                        // alias
    int*   Kaux  = (int*)(P2 + B * T);        // 2*B ints

    hipMemsetAsync(loss, 0, sizeof(float), stream);

    hipLaunchKernelGGL(w2_kernel, dim3(193), dim3(256), 0, stream,
                       conv_w, conv_b, lin_w, lin_b, w2f, bias2);

    hipLaunchKernelGGL(pdot_kernel, dim3(B * T / 4), dim3(256), 0, stream,
                       h, w2f, P0, P1, P2);

    hipLaunchKernelGGL(combine_kernel, dim3(B * T / 256), dim3(256), 0, stream,
                       P0, P1, P2, bias2, alpha, loss);

    hipLaunchKernelGGL(fire_scan, dim3(1), dim3(64), 0, stream,
                       alpha, F, A1, REM, Kaux);

    hipLaunchKernelGGL(gather_kernel, dim3(B * T / 4), dim3(256), 0, stream,
                       h, alpha, F, A1, REM, Kaux, out);
}

// Round 5
// 41.296 us; speedup vs baseline: 25.8090x; 4.2100x over previous
//
#include <hip/hip_runtime.h>
#include <math.h>

constexpr int B = 16, T = 2048, C = 256;

// ---------------------------------------------------------------------------
// Kernel 1: fuse conv_w [C_out, C_in, 3] with lin_w [C_out] -> w2f[3*C], and
// bias2 = lin_w . conv_b + lin_b. One wave per output element (769 waves).
// w2f layout [k][i]: preact(t) = sum_i w2f[0][i]*h[t-1,i] + w2f[1][i]*h[t,i]
//                              + w2f[2][i]*h[t+1,i] + bias2
// ---------------------------------------------------------------------------
__global__ void w2_kernel(const float* __restrict__ conv_w,
                          const float* __restrict__ conv_b,
                          const float* __restrict__ lin_w,
                          const float* __restrict__ lin_b,
                          float* __restrict__ w2f,
                          float* __restrict__ bias2) {
    int gid  = blockIdx.x * blockDim.x + threadIdx.x;
    int wv   = gid >> 6;
    int lane = gid & 63;
    if (wv > 768) return;
    float s = 0.f;
    if (wv < 768) {
        int i = wv & 255, k = wv >> 8;   // wv = k*256 + i
#pragma unroll
        for (int m = 0; m < 4; ++m) {
            int o = lane + 64 * m;
            s = fmaf(lin_w[o], conv_w[((size_t)o * C + i) * 3 + k], s);
        }
    } else {
#pragma unroll
        for (int m = 0; m < 4; ++m) {
            int o = lane + 64 * m;
            s = fmaf(lin_w[o], conv_b[o], s);
        }
    }
#pragma unroll
    for (int off = 32; off; off >>= 1) s += __shfl_down(s, off);
    if (lane == 0) {
        if (wv < 768) w2f[wv] = s;
        else          *bias2 = s + lin_b[0];
    }
}

// ---------------------------------------------------------------------------
// Kernel 2: per-frame partial dots. One wave per (b,t); lane owns 4 channels.
// P_k[bt] = dot(w2f[k], h[b,t,:]).  h is read exactly once (32 MB).
// ---------------------------------------------------------------------------
__global__ void pdot_kernel(const float* __restrict__ h,
                            const float* __restrict__ w2f,
                            float* __restrict__ P0,
                            float* __restrict__ P1,
                            float* __restrict__ P2) {
    int gid  = blockIdx.x * blockDim.x + threadIdx.x;
    int wv   = gid >> 6;
    int lane = gid & 63;
    if (wv >= B * T) return;
    const float4* w4 = (const float4*)w2f;
    float4 w0 = w4[lane], w1 = w4[64 + lane], w2 = w4[128 + lane];
    float4 hv = ((const float4*)h)[(size_t)wv * 64 + lane];
    float s0 = hv.x * w0.x + hv.y * w0.y + hv.z * w0.z + hv.w * w0.w;
    float s1 = hv.x * w1.x + hv.y * w1.y + hv.z * w1.z + hv.w * w1.w;
    float s2 = hv.x * w2.x + hv.y * w2.y + hv.z * w2.z + hv.w * w2.w;
#pragma unroll
    for (int off = 32; off; off >>= 1) {
        s0 += __shfl_down(s0, off);
        s1 += __shfl_down(s1, off);
        s2 += __shfl_down(s2, off);
    }
    if (lane == 0) { P0[wv] = s0; P1[wv] = s1; P2[wv] = s2; }
}

// ---------------------------------------------------------------------------
// Kernel 3: fused alpha + loss + parallel fire computation via prefix sum.
// One block (256 threads) per batch row; 8 frames per thread.
//   aa_t == S_t - floor(S_t)  where S is the prefix sum of alpha, so
//   fire at t  <=>  floor(S_t) > floor(S_{t-1}),  fire index j = floor(S_{t-1}),
//   a1 = (j+1) - S_{t-1},  rem = S_t - floor(S_t),
//   K = floor(S_{T-1}),  tail = (S_{T-1} - K) >= 0.5.
// F/A1/REM alias P0/P1/P2: all P reads precede the __syncthreads(), all
// F/A1/REM writes follow it, and each block touches only its own batch range.
// ---------------------------------------------------------------------------
__global__ void scan_kernel(const float* __restrict__ P0,
                            const float* __restrict__ P1,
                            const float* __restrict__ P2,
                            const float* __restrict__ bias2,
                            float* __restrict__ alpha,
                            int*   __restrict__ F,
                            float* __restrict__ A1,
                            float* __restrict__ REM,
                            int*   __restrict__ Kaux,
                            float* __restrict__ loss) {
    __shared__ float wsum[4];
    int b    = blockIdx.x;
    int tid  = threadIdx.x;        // 0..255
    int lane = tid & 63, wid = tid >> 6;
    size_t base = (size_t)b * T;
    float bias = *bias2;

    // ---- phase 1: alpha for this thread's 8 frames (all P reads here) ----
    int t0 = tid * 8;
    float a[8];
    float s8 = 0.f;
#pragma unroll
    for (int j = 0; j < 8; ++j) {
        int t = t0 + j;
        size_t bt = base + t;
        float pre = P1[bt] + bias;
        if (t > 0)     pre += P0[bt - 1];
        if (t < T - 1) pre += P2[bt + 1];
        float av = 1.f / (1.f + expf(-pre));
        a[j] = av;
        s8 += av;
    }

    // ---- block-level exclusive scan of per-thread sums ----
    float x = s8;
#pragma unroll
    for (int off = 1; off < 64; off <<= 1) {
        float y = __shfl_up(x, off);
        if (lane >= off) x += y;
    }
    if (lane == 63) wsum[wid] = x;
    __syncthreads();                       // also orders P reads before F writes
    float woff = 0.f;
#pragma unroll
    for (int w = 0; w < 4; ++w)
        if (w < wid) woff += wsum[w];
    float Sprev = woff + (x - s8);         // exclusive prefix = S_{t0-1}

    if (tid == 0)
        atomicAdd(loss, wsum[0] + wsum[1] + wsum[2] + wsum[3]);

    // ---- phase 2: per-frame fire detection + writes ----
    int*   Fb = F   + base;
    float* Ab = A1  + base;
    float* Rb = REM + base;
#pragma unroll
    for (int j = 0; j < 8; ++j) {
        int t = t0 + j;
        float S  = Sprev + a[j];
        float kp = floorf(Sprev);
        float k  = floorf(S);
        if (k > kp) {                      // integer crossing => fire at t
            int ji = (int)kp;
            Fb[ji] = t;
            Ab[ji] = (kp + 1.0f) - Sprev;  // a1 = TH - aa_{t-1}
            Rb[ji] = S - k;                // rem carried into next cell
        }
        alpha[base + t] = a[j];
        Sprev = S;
    }
    if (tid == 255) {
        float K = floorf(Sprev);
        Kaux[2 * b]     = (int)K;
        Kaux[2 * b + 1] = (Sprev - K >= 0.5f) ? 1 : 0;
    }
}

// ---------------------------------------------------------------------------
// Kernel 4: gather. One wave per output row (b, j); lane owns 4 channels.
// out[j] = REM[j-1]*h[s] + sum_{s<t<e} alpha[t]*h[t] + A1[j]*h[e],
// accumulated in ascending-t order (matches reference hacc order).
// Rows past the fire count are written as zeros (no memset needed).
// ---------------------------------------------------------------------------
__global__ void gather_kernel(const float* __restrict__ h,
                              const float* __restrict__ alpha,
                              const int*   __restrict__ F,
                              const float* __restrict__ A1,
                              const float* __restrict__ REM,
                              const int*   __restrict__ Kaux,
                              float* __restrict__ out) {
    int gid  = blockIdx.x * blockDim.x + threadIdx.x;
    int wv   = gid >> 6;
    int lane = gid & 63;
    if (wv >= B * T) return;
    int b = wv >> 11;
    int j = wv & (T - 1);
    int K    = Kaux[2 * b];
    int tail = Kaux[2 * b + 1];
    float4* orow = (float4*)(out + ((size_t)b * T + j) * C) + lane;
    if (j > K || (j == K && !tail)) {
        *orow = make_float4(0.f, 0.f, 0.f, 0.f);
        return;
    }
    const float*  ab = alpha + (size_t)b * T;
    const float4* hb = (const float4*)(h + (size_t)b * T * C);
    const int*    Fb = F + (size_t)b * T;

    float4 acc;
    int t;
    if (j > 0) {
        int s = Fb[j - 1];
        float r = REM[(size_t)b * T + j - 1];
        float4 hv = hb[(size_t)s * 64 + lane];
        acc = make_float4(r * hv.x, r * hv.y, r * hv.z, r * hv.w);
        t = s + 1;
    } else {
        acc = make_float4(0.f, 0.f, 0.f, 0.f);
        t = 0;
    }
    int mid_end = (j == K) ? T : Fb[j];
    for (; t < mid_end; ++t) {
        float a = ab[t];
        float4 hv = hb[(size_t)t * 64 + lane];
        acc.x = fmaf(a, hv.x, acc.x);
        acc.y = fmaf(a, hv.y, acc.y);
        acc.z = fmaf(a, hv.z, acc.z);
        acc.w = fmaf(a, hv.w, acc.w);
    }
    if (j < K) {
        float a1 = A1[(size_t)b * T + j];
        float4 hv = hb[(size_t)mid_end * 64 + lane];
        acc.x = fmaf(a1, hv.x, acc.x);
        acc.y = fmaf(a1, hv.y, acc.y);
        acc.z = fmaf(a1, hv.z, acc.z);
        acc.w = fmaf(a1, hv.w, acc.w);
    }
    *orow = acc;
}

// ---------------------------------------------------------------------------
extern "C" void kernel_launch(void* const* d_in, const int* in_sizes, int n_in,
                              void* d_out, int out_size, void* d_ws, size_t ws_size,
                              hipStream_t stream) {
    const float* h      = (const float*)d_in[0];
    // d_in[1] = hs_mask (unused by the math)
    const float* conv_w = (const float*)d_in[2];
    const float* conv_b = (const float*)d_in[3];
    const float* lin_w  = (const float*)d_in[4];
    const float* lin_b  = (const float*)d_in[5];

    float* out  = (float*)d_out;
    float* loss = out + (size_t)B * T * C;   // last element of d_out

    // workspace layout (floats):
    //   w2f[768] | bias2 (pad to 1024) | alpha[B*T] | P0[B*T] | P1[B*T] | P2[B*T] | Kaux
    // F/A1/REM alias P0/P1/P2 (safe: see scan_kernel comment).
    float* w2f   = (float*)d_ws;
    float* bias2 = w2f + 768;
    float* alpha = w2f + 1024;
    float* P0    = alpha + B * T;
    float* P1    = P0 + B * T;
    float* P2    = P1 + B * T;
    int*   F     = (int*)P0;
    float* A1    = P1;
    float* REM   = P2;
    int*   Kaux  = (int*)(P2 + B * T);        // 2*B ints

    hipMemsetAsync(loss, 0, sizeof(float), stream);

    hipLaunchKernelGGL(w2_kernel, dim3(193), dim3(256), 0, stream,
                       conv_w, conv_b, lin_w, lin_b, w2f, bias2);

    hipLaunchKernelGGL(pdot_kernel, dim3(B * T / 4), dim3(256), 0, stream,
                       h, w2f, P0, P1, P2);

    hipLaunchKernelGGL(scan_kernel, dim3(B), dim3(256), 0, stream,
                       P0, P1, P2, bias2, alpha, F, A1, REM, Kaux, loss);

    hipLaunchKernelGGL(gather_kernel, dim3(B * T / 4), dim3(256), 0, stream,
                       h, alpha, F, A1, REM, Kaux, out);
}